// Round 5
// baseline (3632.617 us; speedup 1.0000x reference)
//
#include <hip/hip_runtime.h>

typedef _Float16 f16;
typedef _Float16 f16x2 __attribute__((ext_vector_type(2)));
typedef _Float16 f16x8 __attribute__((ext_vector_type(8)));
typedef __fp16   h16x2 __attribute__((ext_vector_type(2)));
typedef float    f32x4 __attribute__((ext_vector_type(4)));

#define B_ 32
#define S_ 2048
#define E_ 256
#define H_ 256
#define M_ (B_ * S_)   // 65536

union U32F2 { unsigned int u; f16x2 h; h16x2 g; };

__device__ __forceinline__ float fdot2f(f16x2 a, f16x2 b, float c) {
#if __has_builtin(__builtin_amdgcn_fdot2)
  return __builtin_amdgcn_fdot2(a, b, c, false);
#else
  return c + (float)a.x * (float)b.x + (float)a.y * (float)b.y;
#endif
}
__device__ __forceinline__ float fdot2u(unsigned int w, unsigned int v, float c) {
  U32F2 a, b; a.u = w; b.u = v;
  return fdot2f(a.h, b.h, c);
}

__device__ __forceinline__ float fast_exp2(float x) {
#if __has_builtin(__builtin_amdgcn_exp2f)
  return __builtin_amdgcn_exp2f(x);
#else
  return exp2f(x);
#endif
}
__device__ __forceinline__ float fast_rcp(float x) {
#if __has_builtin(__builtin_amdgcn_rcpf)
  return __builtin_amdgcn_rcpf(x);
#else
  return 1.0f / x;
#endif
}
__device__ __forceinline__ float sigm(float x) {
  float e = fast_exp2(-1.4426950408889634f * x);
  return fast_rcp(1.0f + e);
}
__device__ __forceinline__ float tanh_fast(float x) {
  x = fminf(15.0f, fmaxf(-15.0f, x));
  float e = fast_exp2(2.8853900817779268f * x); // exp(2x)
  return (e - 1.0f) * fast_rcp(e + 1.0f);
}

// ---------------------------------------------------------------------------
// Kernel A: Xg[g][m][h] = (x @ W_g) in f16, g in {z,r,h}, m = b*S + s.
// (unchanged from round 3 — ~225us, revisit after the recurrence is fixed)
// ---------------------------------------------------------------------------
__global__ __launch_bounds__(256, 4) void proj_gemm(
    const float* __restrict__ x, const float* __restrict__ Wz,
    const float* __restrict__ Wr, const float* __restrict__ Wh,
    f16* __restrict__ Xg) {
  __shared__ __align__(16) f16 Wl[64][264];
  const int tid = threadIdx.x;
  const int wv = tid >> 6;
  const int ln = tid & 63;
  const int M0 = blockIdx.x * 64;
  const int nb = blockIdx.y;           // 0..11
  const int gate = nb >> 2;            // 0,1,2
  const int c0 = (nb & 3) * 64;        // col base within gate
  const float* W = (gate == 0) ? Wz : (gate == 1 ? Wr : Wh);

#pragma unroll
  for (int i = 0; i < 64; ++i) {
    int e = i * 256 + tid;
    int cl = e & 63;
    int k = e >> 6;
    Wl[cl][k] = (f16)W[(size_t)k * H_ + c0 + cl];
  }
  __syncthreads();

  const int row = M0 + wv * 16 + (ln & 15);
  const int kg = (ln >> 4) * 8;
  f32x4 acc0 = {0.f, 0.f, 0.f, 0.f};
  f32x4 acc1 = {0.f, 0.f, 0.f, 0.f};
  f32x4 acc2 = {0.f, 0.f, 0.f, 0.f};
  f32x4 acc3 = {0.f, 0.f, 0.f, 0.f};

#pragma unroll
  for (int kk = 0; kk < 8; ++kk) {
    const int k0 = kk * 32;
    const float* ap = x + (size_t)row * E_ + k0 + kg;
    float4 a0 = *(const float4*)ap;
    float4 a1 = *(const float4*)(ap + 4);
    f16x8 af = {(f16)a0.x, (f16)a0.y, (f16)a0.z, (f16)a0.w,
                (f16)a1.x, (f16)a1.y, (f16)a1.z, (f16)a1.w};
    f16x8 b0 = *(const f16x8*)&Wl[0 * 16 + (ln & 15)][k0 + kg];
    f16x8 b1 = *(const f16x8*)&Wl[1 * 16 + (ln & 15)][k0 + kg];
    f16x8 b2 = *(const f16x8*)&Wl[2 * 16 + (ln & 15)][k0 + kg];
    f16x8 b3 = *(const f16x8*)&Wl[3 * 16 + (ln & 15)][k0 + kg];
    acc0 = __builtin_amdgcn_mfma_f32_16x16x32_f16(af, b0, acc0, 0, 0, 0);
    acc1 = __builtin_amdgcn_mfma_f32_16x16x32_f16(af, b1, acc1, 0, 0, 0);
    acc2 = __builtin_amdgcn_mfma_f32_16x16x32_f16(af, b2, acc2, 0, 0, 0);
    acc3 = __builtin_amdgcn_mfma_f32_16x16x32_f16(af, b3, acc3, 0, 0, 0);
  }

  f16* outg = Xg + (size_t)gate * ((size_t)M_ * H_);
  const int rbase = M0 + wv * 16 + (ln >> 4) * 4;
#define EPI(NT, ACC)                                                       \
  {                                                                        \
    const int cc = c0 + NT * 16 + (ln & 15);                               \
    outg[(size_t)(rbase + 0) * H_ + cc] = (f16)ACC[0];                     \
    outg[(size_t)(rbase + 1) * H_ + cc] = (f16)ACC[1];                     \
    outg[(size_t)(rbase + 2) * H_ + cc] = (f16)ACC[2];                     \
    outg[(size_t)(rbase + 3) * H_ + cc] = (f16)ACC[3];                     \
  }
  EPI(0, acc0) EPI(1, acc1) EPI(2, acc2) EPI(3, acc3)
#undef EPI
}

// ---------------------------------------------------------------------------
// Kernel B: recurrence. 32 wgs (one per batch), 1024 threads (16 waves).
// Lane owns column c = wv*16 + (ln&15) and K-quarter kq = ln>>4 (64 rows).
// Weight footprint: 96 VGPRs/lane (32 packed f16 pairs x 3 gates) -> total
// pressure ~125, fits the compiler's 128-VGPR / 4-waves-per-EU target.
// (Rounds 3-4 showed 192-reg variant gets its weight loads rematerialized
// from L2 every step at the 128 budget: 2.9ms, VALUBusy 7%.)
// Weights are pinned with empty inline asm so the allocator cannot
// rematerialize the global loads; worst case is a small scratch spill.
// h / r*h exchanged as packed f16 pairs via quarter-padded LDS (576B each,
// conflict-free broadcast ds_read_b128). Two __syncthreads per step.
// ---------------------------------------------------------------------------
__global__ __launch_bounds__(1024) void gru_rec(
    const f16* __restrict__ Xg, const float* __restrict__ h0,
    const float* __restrict__ Uz, const float* __restrict__ Ur,
    const float* __restrict__ Uh, float* __restrict__ out) {
  // 128 pair-dwords, quarter q at dword offset q*36 (16B-aligned, banks 4q..)
  __shared__ __align__(16) unsigned int h2v[4 * 36];
  __shared__ __align__(16) unsigned int rh2v[4 * 36];
  const int b = blockIdx.x;
  const int tid = threadIdx.x;
  const int wv = tid >> 6;             // 0..15
  const int ln = tid & 63;
  const int c = wv * 16 + (ln & 15);   // 0..255 output column
  const int kq = ln >> 4;              // 0..3 K-quarter
  const bool owner = (kq == 0);

  // ---- preload this lane's weight quarter (packed f16 pairs along K) ----
  unsigned int wzU[32], wrU[32], whU[32];
  {
    const int rb = kq * 64;
#pragma unroll
    for (int j = 0; j < 32; ++j) {
      const size_t o0 = (size_t)(rb + 2 * j) * H_ + c;
      U32F2 pz, pr, ph;
      pz.h = f16x2{(f16)Uz[o0], (f16)Uz[o0 + H_]};
      pr.h = f16x2{(f16)Ur[o0], (f16)Ur[o0 + H_]};
      ph.h = f16x2{(f16)Uh[o0], (f16)Uh[o0 + H_]};
      wzU[j] = pz.u; wrU[j] = pr.u; whU[j] = ph.u;
    }
  }
  // pin: make values opaque so they cannot be rematerialized from global
#pragma unroll
  for (int j = 0; j < 32; ++j) {
    asm("" : "+v"(wzU[j]));
    asm("" : "+v"(wrU[j]));
    asm("" : "+v"(whU[j]));
  }

  // ---- init h ----
  float h_reg = 0.f;
  if (owner) h_reg = h0[b * H_ + c];
  {
    float hn = __shfl_xor(h_reg, 1);
    if (owner && !(ln & 1)) {
      U32F2 p; p.g = __builtin_amdgcn_cvt_pkrtz(h_reg, hn);
      const int pi = c >> 1;
      h2v[(pi >> 5) * 36 + (pi & 31)] = p.u;
    }
  }
  __syncthreads();

  const f16* xz = Xg + (size_t)b * ((size_t)S_ * H_) + c;
  const f16* xr = xz + (size_t)M_ * H_;
  const f16* xh = xr + (size_t)M_ * H_;
  float* outp = out + (size_t)b * ((size_t)S_ * H_) + c;

  // prefetch x values for t=0
  f16 pz = xz[0], pr = xr[0], ph = xh[0];

  const uint4* hq = (const uint4*)(h2v + kq * 36);
  const uint4* rq = (const uint4*)(rh2v + kq * 36);

  for (int t = 0; t < S_; ++t) {
    const float xzc = (float)pz, xrc = (float)pr, xhc = (float)ph;
    {  // prefetch t+1
      const int t2 = (t + 1 < S_) ? (t + 1) : t;
      const size_t off = (size_t)t2 * H_;
      pz = xz[off]; pr = xr[off]; ph = xh[off];
    }

    // ---- phase 1: z and r partial dots over this K-quarter ----
    float az = 0.f, ar = 0.f;
#pragma unroll
    for (int i = 0; i < 8; ++i) {
      uint4 hv = hq[i];
      az = fdot2u(wzU[4 * i + 0], hv.x, az);
      az = fdot2u(wzU[4 * i + 1], hv.y, az);
      az = fdot2u(wzU[4 * i + 2], hv.z, az);
      az = fdot2u(wzU[4 * i + 3], hv.w, az);
      ar = fdot2u(wrU[4 * i + 0], hv.x, ar);
      ar = fdot2u(wrU[4 * i + 1], hv.y, ar);
      ar = fdot2u(wrU[4 * i + 2], hv.z, ar);
      ar = fdot2u(wrU[4 * i + 3], hv.w, ar);
    }
    az += __shfl_xor(az, 16); az += __shfl_xor(az, 32);
    ar += __shfl_xor(ar, 16); ar += __shfl_xor(ar, 32);

    float z_s = 0.f, rh = 0.f;
    if (owner) {
      z_s = sigm(az + xzc);
      float rr = sigm(ar + xrc);
      rh = rr * h_reg;
    }
    {
      float rhn = __shfl_xor(rh, 1);
      if (owner && !(ln & 1)) {
        U32F2 p; p.g = __builtin_amdgcn_cvt_pkrtz(rh, rhn);
        const int pi = c >> 1;
        rh2v[(pi >> 5) * 36 + (pi & 31)] = p.u;
      }
    }
    __syncthreads();

    // ---- phase 2: candidate partial dot over r*h (2 chains) ----
    float ah0 = 0.f, ah1 = 0.f;
#pragma unroll
    for (int i = 0; i < 8; ++i) {
      uint4 rv = rq[i];
      ah0 = fdot2u(whU[4 * i + 0], rv.x, ah0);
      ah1 = fdot2u(whU[4 * i + 1], rv.y, ah1);
      ah0 = fdot2u(whU[4 * i + 2], rv.z, ah0);
      ah1 = fdot2u(whU[4 * i + 3], rv.w, ah1);
    }
    float ah = ah0 + ah1;
    ah += __shfl_xor(ah, 16); ah += __shfl_xor(ah, 32);

    if (owner) {
      float ht = tanh_fast(ah + xhc);
      h_reg = h_reg + z_s * (ht - h_reg);     // (1-z)h + z*h~
      outp[(size_t)t * H_] = h_reg;
    }
    {
      float hn = __shfl_xor(h_reg, 1);
      if (owner && !(ln & 1)) {
        U32F2 p; p.g = __builtin_amdgcn_cvt_pkrtz(h_reg, hn);
        const int pi = c >> 1;
        h2v[(pi >> 5) * 36 + (pi & 31)] = p.u;
      }
    }
    __syncthreads();
  }
}

extern "C" void kernel_launch(void* const* d_in, const int* in_sizes, int n_in,
                              void* d_out, int out_size, void* d_ws,
                              size_t ws_size, hipStream_t stream) {
  const float* x  = (const float*)d_in[0];
  const float* h0 = (const float*)d_in[1];
  const float* Wz = (const float*)d_in[2];
  const float* Uz = (const float*)d_in[3];
  const float* Wr = (const float*)d_in[4];
  const float* Ur = (const float*)d_in[5];
  const float* Wh = (const float*)d_in[6];
  const float* Uh = (const float*)d_in[7];
  float* out = (float*)d_out;

  const size_t need = (size_t)3 * M_ * H_ * sizeof(f16);  // 100.7 MB
  if (ws_size < need) return;
  f16* Xg = (f16*)d_ws;

  proj_gemm<<<dim3(M_ / 64, 12), 256, 0, stream>>>(x, Wz, Wr, Wh, Xg);
  gru_rec<<<dim3(B_), 1024, 0, stream>>>(Xg, h0, Uz, Ur, Uh, out);
}

// Round 8
// 3381.803 us; speedup vs baseline: 1.0742x; 1.0742x over previous
//
#include <hip/hip_runtime.h>

typedef _Float16 f16;
typedef _Float16 f16x2 __attribute__((ext_vector_type(2)));
typedef _Float16 f16x8 __attribute__((ext_vector_type(8)));
typedef __fp16   h16x2 __attribute__((ext_vector_type(2)));
typedef float    f32x4 __attribute__((ext_vector_type(4)));

#define B_ 32
#define S_ 2048
#define E_ 256
#define H_ 256
#define M_ (B_ * S_)   // 65536

union U32F2 { unsigned int u; f16x2 h; h16x2 g; };

__device__ __forceinline__ float fdot2f(f16x2 a, f16x2 b, float c) {
#if __has_builtin(__builtin_amdgcn_fdot2)
  return __builtin_amdgcn_fdot2(a, b, c, false);
#else
  return c + (float)a.x * (float)b.x + (float)a.y * (float)b.y;
#endif
}
__device__ __forceinline__ float fdot2u(unsigned int w, unsigned int v, float c) {
  U32F2 a, b; a.u = w; b.u = v;
  return fdot2f(a.h, b.h, c);
}

__device__ __forceinline__ float fast_exp2(float x) {
#if __has_builtin(__builtin_amdgcn_exp2f)
  return __builtin_amdgcn_exp2f(x);
#else
  return exp2f(x);
#endif
}
__device__ __forceinline__ float fast_rcp(float x) {
#if __has_builtin(__builtin_amdgcn_rcpf)
  return __builtin_amdgcn_rcpf(x);
#else
  return 1.0f / x;
#endif
}
__device__ __forceinline__ float sigm(float x) {
  float e = fast_exp2(-1.4426950408889634f * x);
  return fast_rcp(1.0f + e);
}
__device__ __forceinline__ float tanh_fast(float x) {
  x = fminf(15.0f, fmaxf(-15.0f, x));
  float e = fast_exp2(2.8853900817779268f * x); // exp(2x)
  return (e - 1.0f) * fast_rcp(e + 1.0f);
}

// ---------------------------------------------------------------------------
// Kernel A: Xg[g][m][h] = (x @ W_g) in f16, g in {z,r,h}. Unchanged (passed,
// ~200us); revisit only after the recurrence is at its floor.
// ---------------------------------------------------------------------------
__global__ __launch_bounds__(256, 4) void proj_gemm(
    const float* __restrict__ x, const float* __restrict__ Wz,
    const float* __restrict__ Wr, const float* __restrict__ Wh,
    f16* __restrict__ Xg) {
  __shared__ __align__(16) f16 Wl[64][264];
  const int tid = threadIdx.x;
  const int wv = tid >> 6;
  const int ln = tid & 63;
  const int M0 = blockIdx.x * 64;
  const int nb = blockIdx.y;           // 0..11
  const int gate = nb >> 2;            // 0,1,2
  const int c0 = (nb & 3) * 64;        // col base within gate
  const float* W = (gate == 0) ? Wz : (gate == 1 ? Wr : Wh);

#pragma unroll
  for (int i = 0; i < 64; ++i) {
    int e = i * 256 + tid;
    int cl = e & 63;
    int k = e >> 6;
    Wl[cl][k] = (f16)W[(size_t)k * H_ + c0 + cl];
  }
  __syncthreads();

  const int row = M0 + wv * 16 + (ln & 15);
  const int kg = (ln >> 4) * 8;
  f32x4 acc0 = {0.f, 0.f, 0.f, 0.f};
  f32x4 acc1 = {0.f, 0.f, 0.f, 0.f};
  f32x4 acc2 = {0.f, 0.f, 0.f, 0.f};
  f32x4 acc3 = {0.f, 0.f, 0.f, 0.f};

#pragma unroll
  for (int kk = 0; kk < 8; ++kk) {
    const int k0 = kk * 32;
    const float* ap = x + (size_t)row * E_ + k0 + kg;
    float4 a0 = *(const float4*)ap;
    float4 a1 = *(const float4*)(ap + 4);
    f16x8 af = {(f16)a0.x, (f16)a0.y, (f16)a0.z, (f16)a0.w,
                (f16)a1.x, (f16)a1.y, (f16)a1.z, (f16)a1.w};
    f16x8 b0 = *(const f16x8*)&Wl[0 * 16 + (ln & 15)][k0 + kg];
    f16x8 b1 = *(const f16x8*)&Wl[1 * 16 + (ln & 15)][k0 + kg];
    f16x8 b2 = *(const f16x8*)&Wl[2 * 16 + (ln & 15)][k0 + kg];
    f16x8 b3 = *(const f16x8*)&Wl[3 * 16 + (ln & 15)][k0 + kg];
    acc0 = __builtin_amdgcn_mfma_f32_16x16x32_f16(af, b0, acc0, 0, 0, 0);
    acc1 = __builtin_amdgcn_mfma_f32_16x16x32_f16(af, b1, acc1, 0, 0, 0);
    acc2 = __builtin_amdgcn_mfma_f32_16x16x32_f16(af, b2, acc2, 0, 0, 0);
    acc3 = __builtin_amdgcn_mfma_f32_16x16x32_f16(af, b3, acc3, 0, 0, 0);
  }

  f16* outg = Xg + (size_t)gate * ((size_t)M_ * H_);
  const int rbase = M0 + wv * 16 + (ln >> 4) * 4;
#define EPI(NT, ACC)                                                       \
  {                                                                        \
    const int cc = c0 + NT * 16 + (ln & 15);                               \
    outg[(size_t)(rbase + 0) * H_ + cc] = (f16)ACC[0];                     \
    outg[(size_t)(rbase + 1) * H_ + cc] = (f16)ACC[1];                     \
    outg[(size_t)(rbase + 2) * H_ + cc] = (f16)ACC[2];                     \
    outg[(size_t)(rbase + 3) * H_ + cc] = (f16)ACC[3];                     \
  }
  EPI(0, acc0) EPI(1, acc1) EPI(2, acc2) EPI(3, acc3)
#undef EPI
}

// ---------------------------------------------------------------------------
// Kernel B: recurrence. 32 wgs (one per batch), 512 threads (8 waves).
// Lane owns TWO columns {c, c+128} (c = wv*16 + (ln&15)) and K-quarter
// kq = ln>>4 (64 K-rows). Weights: 192 packed-f16-pair dwords per lane.
//
// THE KEY TRICK: a 96KB LDS pad caps occupancy at 1 wg/CU = 2 waves/SIMD,
// which forces the compiler's VGPR budget to 256 — so the 192 pinned weight
// regs stay resident. (R3/R4: 128-VGPR budget -> weights rematerialized
// from L2 every step, 2.9ms. R5: 64-VGPR budget -> pinned weights spilled
// to scratch, 3.4ms.)
//
// h / r*h exchanged as packed f16 pairs via quarter-padded LDS (36 dwords
// per quarter -> 16 distinct banks across the 4 broadcast lines,
// conflict-free ds_read_b128). Two __syncthreads per step.
// ---------------------------------------------------------------------------
__global__ __launch_bounds__(512) void gru_rec(
    const f16* __restrict__ Xg, const float* __restrict__ h0,
    const float* __restrict__ Uz, const float* __restrict__ Ur,
    const float* __restrict__ Uh, float* __restrict__ out) {
  // 96KB: occupancy-forcing pad. h pairs at [0..144), rh pairs at [160..304).
  __shared__ __align__(16) unsigned int lds[24576];
  unsigned int* h2v = lds;          // 4 quarters x 36 dwords
  unsigned int* rh2v = lds + 160;   // byte 640, 16B aligned

  const int b = blockIdx.x;
  const int tid = threadIdx.x;
  const int wv = tid >> 6;             // 0..7
  const int ln = tid & 63;
  const int c = wv * 16 + (ln & 15);   // first owned column (0..127)
  const int kq = ln >> 4;              // K-quarter 0..3
  const bool owner = (kq == 0);        // ln < 16

  // ---- preload weight quarters for both columns (packed pairs along K) ---
  unsigned int wz0[32], wz1[32], wr0[32], wr1[32], wh0[32], wh1[32];
  {
    const int rb = kq * 64;
#pragma unroll
    for (int j = 0; j < 32; ++j) {
      const size_t o = (size_t)(rb + 2 * j) * H_ + c;
      U32F2 t;
      t.h = f16x2{(f16)Uz[o], (f16)Uz[o + H_]};             wz0[j] = t.u;
      t.h = f16x2{(f16)Uz[o + 128], (f16)Uz[o + H_ + 128]}; wz1[j] = t.u;
      t.h = f16x2{(f16)Ur[o], (f16)Ur[o + H_]};             wr0[j] = t.u;
      t.h = f16x2{(f16)Ur[o + 128], (f16)Ur[o + H_ + 128]}; wr1[j] = t.u;
      t.h = f16x2{(f16)Uh[o], (f16)Uh[o + H_]};             wh0[j] = t.u;
      t.h = f16x2{(f16)Uh[o + 128], (f16)Uh[o + H_ + 128]}; wh1[j] = t.u;
    }
  }
  // pin: forbid rematerialization of the weight loads
#pragma unroll
  for (int j = 0; j < 32; ++j) {
    asm("" : "+v"(wz0[j])); asm("" : "+v"(wz1[j]));
    asm("" : "+v"(wr0[j])); asm("" : "+v"(wr1[j]));
    asm("" : "+v"(wh0[j])); asm("" : "+v"(wh1[j]));
  }

  // ---- init h ----
  float h_reg0 = 0.f, h_reg1 = 0.f;
  if (owner) {
    h_reg0 = h0[b * H_ + c];
    h_reg1 = h0[b * H_ + c + 128];
  }
  {
    float hn0 = __shfl_xor(h_reg0, 1);
    float hn1 = __shfl_xor(h_reg1, 1);
    if (owner && !(ln & 1)) {
      U32F2 p0, p1;
      p0.g = __builtin_amdgcn_cvt_pkrtz(h_reg0, hn0);
      p1.g = __builtin_amdgcn_cvt_pkrtz(h_reg1, hn1);
      const int pi0 = c >> 1, pi1 = (c >> 1) + 64;
      h2v[(pi0 >> 5) * 36 + (pi0 & 31)] = p0.u;
      h2v[(pi1 >> 5) * 36 + (pi1 & 31)] = p1.u;
    }
  }
  __syncthreads();

  const f16* xz = Xg + (size_t)b * ((size_t)S_ * H_) + c;
  const f16* xr = xz + (size_t)M_ * H_;
  const f16* xh = xr + (size_t)M_ * H_;
  float* outp = out + (size_t)b * ((size_t)S_ * H_) + c;

  // prefetch x values for t=0 (both columns)
  f16 pz0 = 0, pr0 = 0, ph0 = 0, pz1 = 0, pr1 = 0, ph1 = 0;
  if (owner) {
    pz0 = xz[0]; pr0 = xr[0]; ph0 = xh[0];
    pz1 = xz[128]; pr1 = xr[128]; ph1 = xh[128];
  }

  const uint4* hq = (const uint4*)(h2v + kq * 36);
  const uint4* rq = (const uint4*)(rh2v + kq * 36);

  for (int t = 0; t < S_; ++t) {
    const float xz0c = (float)pz0, xr0c = (float)pr0, xh0c = (float)ph0;
    const float xz1c = (float)pz1, xr1c = (float)pr1, xh1c = (float)ph1;
    if (owner) {  // prefetch t+1
      const int t2 = (t + 1 < S_) ? (t + 1) : t;
      const size_t off = (size_t)t2 * H_;
      pz0 = xz[off]; pr0 = xr[off]; ph0 = xh[off];
      pz1 = xz[off + 128]; pr1 = xr[off + 128]; ph1 = xh[off + 128];
    }

    // ---- phase 1: z and r partial dots (4 ILP chains) ----
    float az0 = 0.f, az1 = 0.f, ar0 = 0.f, ar1 = 0.f;
#pragma unroll
    for (int i = 0; i < 8; ++i) {
      uint4 hv = hq[i];
      az0 = fdot2u(wz0[4 * i + 0], hv.x, az0);
      az0 = fdot2u(wz0[4 * i + 1], hv.y, az0);
      az0 = fdot2u(wz0[4 * i + 2], hv.z, az0);
      az0 = fdot2u(wz0[4 * i + 3], hv.w, az0);
      az1 = fdot2u(wz1[4 * i + 0], hv.x, az1);
      az1 = fdot2u(wz1[4 * i + 1], hv.y, az1);
      az1 = fdot2u(wz1[4 * i + 2], hv.z, az1);
      az1 = fdot2u(wz1[4 * i + 3], hv.w, az1);
      ar0 = fdot2u(wr0[4 * i + 0], hv.x, ar0);
      ar0 = fdot2u(wr0[4 * i + 1], hv.y, ar0);
      ar0 = fdot2u(wr0[4 * i + 2], hv.z, ar0);
      ar0 = fdot2u(wr0[4 * i + 3], hv.w, ar0);
      ar1 = fdot2u(wr1[4 * i + 0], hv.x, ar1);
      ar1 = fdot2u(wr1[4 * i + 1], hv.y, ar1);
      ar1 = fdot2u(wr1[4 * i + 2], hv.z, ar1);
      ar1 = fdot2u(wr1[4 * i + 3], hv.w, ar1);
    }
    az0 += __shfl_xor(az0, 16); az0 += __shfl_xor(az0, 32);
    az1 += __shfl_xor(az1, 16); az1 += __shfl_xor(az1, 32);
    ar0 += __shfl_xor(ar0, 16); ar0 += __shfl_xor(ar0, 32);
    ar1 += __shfl_xor(ar1, 16); ar1 += __shfl_xor(ar1, 32);

    float z0 = 0.f, z1 = 0.f, rh0 = 0.f, rh1 = 0.f;
    if (owner) {
      z0 = sigm(az0 + xz0c);
      z1 = sigm(az1 + xz1c);
      rh0 = sigm(ar0 + xr0c) * h_reg0;
      rh1 = sigm(ar1 + xr1c) * h_reg1;
    }
    {
      float rn0 = __shfl_xor(rh0, 1);
      float rn1 = __shfl_xor(rh1, 1);
      if (owner && !(ln & 1)) {
        U32F2 p0, p1;
        p0.g = __builtin_amdgcn_cvt_pkrtz(rh0, rn0);
        p1.g = __builtin_amdgcn_cvt_pkrtz(rh1, rn1);
        const int pi0 = c >> 1, pi1 = (c >> 1) + 64;
        rh2v[(pi0 >> 5) * 36 + (pi0 & 31)] = p0.u;
        rh2v[(pi1 >> 5) * 36 + (pi1 & 31)] = p1.u;
      }
    }
    __syncthreads();

    // ---- phase 2: candidate partial dots (4 ILP chains) ----
    float a0a = 0.f, a0b = 0.f, a1a = 0.f, a1b = 0.f;
#pragma unroll
    for (int i = 0; i < 8; ++i) {
      uint4 rv = rq[i];
      a0a = fdot2u(wh0[4 * i + 0], rv.x, a0a);
      a0b = fdot2u(wh0[4 * i + 1], rv.y, a0b);
      a0a = fdot2u(wh0[4 * i + 2], rv.z, a0a);
      a0b = fdot2u(wh0[4 * i + 3], rv.w, a0b);
      a1a = fdot2u(wh1[4 * i + 0], rv.x, a1a);
      a1b = fdot2u(wh1[4 * i + 1], rv.y, a1b);
      a1a = fdot2u(wh1[4 * i + 2], rv.z, a1a);
      a1b = fdot2u(wh1[4 * i + 3], rv.w, a1b);
    }
    float ah0 = a0a + a0b, ah1 = a1a + a1b;
    ah0 += __shfl_xor(ah0, 16); ah0 += __shfl_xor(ah0, 32);
    ah1 += __shfl_xor(ah1, 16); ah1 += __shfl_xor(ah1, 32);

    if (owner) {
      float ht0 = tanh_fast(ah0 + xh0c);
      float ht1 = tanh_fast(ah1 + xh1c);
      h_reg0 = h_reg0 + z0 * (ht0 - h_reg0);
      h_reg1 = h_reg1 + z1 * (ht1 - h_reg1);
      outp[(size_t)t * H_] = h_reg0;
      outp[(size_t)t * H_ + 128] = h_reg1;
    }
    {
      float hn0 = __shfl_xor(h_reg0, 1);
      float hn1 = __shfl_xor(h_reg1, 1);
      if (owner && !(ln & 1)) {
        U32F2 p0, p1;
        p0.g = __builtin_amdgcn_cvt_pkrtz(h_reg0, hn0);
        p1.g = __builtin_amdgcn_cvt_pkrtz(h_reg1, hn1);
        const int pi0 = c >> 1, pi1 = (c >> 1) + 64;
        h2v[(pi0 >> 5) * 36 + (pi0 & 31)] = p0.u;
        h2v[(pi1 >> 5) * 36 + (pi1 & 31)] = p1.u;
      }
    }
    __syncthreads();
  }
}

extern "C" void kernel_launch(void* const* d_in, const int* in_sizes, int n_in,
                              void* d_out, int out_size, void* d_ws,
                              size_t ws_size, hipStream_t stream) {
  const float* x  = (const float*)d_in[0];
  const float* h0 = (const float*)d_in[1];
  const float* Wz = (const float*)d_in[2];
  const float* Uz = (const float*)d_in[3];
  const float* Wr = (const float*)d_in[4];
  const float* Ur = (const float*)d_in[5];
  const float* Wh = (const float*)d_in[6];
  const float* Uh = (const float*)d_in[7];
  float* out = (float*)d_out;

  const size_t need = (size_t)3 * M_ * H_ * sizeof(f16);  // 100.7 MB
  if (ws_size < need) return;
  f16* Xg = (f16*)d_ws;

  proj_gemm<<<dim3(M_ / 64, 12), 256, 0, stream>>>(x, Wz, Wr, Wh, Xg);
  gru_rec<<<dim3(B_), 512, 0, stream>>>(Xg, h0, Uz, Ur, Uh, out);
}